// Round 5
// baseline (417.321 us; speedup 1.0000x reference)
//
#include <hip/hip_runtime.h>

// 2D CDF 5/3 lifting wavelet, fused. Input x: (24,1024,1024) fp32.
// Output: (8,12,512,512) fp32, planes LL(0..2) LH(3..5) HL(6..8) HH(9..11).
//
// v7 = v5 (no LDS, no barriers, verified math: absmax 0.0) + unleashed regs.
// Diagnosis history: v2/v4/v6 all ~60-64us at HBM 3.1 TB/s == 50% of the
// 6.3 TB/s achievable -- the barrier/vmcnt(0)-drain phase structure convoys
// all resident blocks (load burst / compute window / store burst) and locks
// HBM duty cycle at ~50%. Coalescing (v6) and occupancy (28-72%) are both
// measured non-levers. v5's barrier-free form failed only because the
// allocator squeezed it to 56 VGPRs, serializing the 32 window loads.
// Fix here:
//   - __launch_bounds__(256, 1): min 1 wave/EU -> VGPR cap 512, allocator
//     free to keep all 32 float4 loads in flight (in-thread MLP does the
//     latency hiding; low occupancy is fine).
//   - all 8 row-windows loaded FIRST into w[8][16] (constant-indexed after
//     unroll -> registers), horizontal+vertical lifting computed after.
// Zero cross-thread communication; waves retire independently -> no
// phase-locking mechanism remains.

static __device__ __forceinline__ int mref(int k) {
    // _rpad reflect in half-res index space (N=512): e[-1]->E[1], e[512]->E[510]
    return k < 0 ? 1 : (k > 511 ? 510 : k);
}

static __device__ __forceinline__ float4 lift_sub(float4 o, float4 em, float4 ep) {
    float4 r;
    r.x = o.x - 0.5f * (em.x + ep.x);
    r.y = o.y - 0.5f * (em.y + ep.y);
    r.z = o.z - 0.5f * (em.z + ep.z);
    r.w = o.w - 0.5f * (em.w + ep.w);
    return r;
}

static __device__ __forceinline__ float4 lift_add(float4 e, float4 dm, float4 dp) {
    float4 r;
    r.x = e.x + 0.25f * (dm.x + dp.x);
    r.y = e.y + 0.25f * (dm.y + dp.y);
    r.z = e.z + 0.25f * (dm.z + dp.z);
    r.w = e.w + 0.25f * (dm.w + dp.w);
    return r;
}

// Horizontal lifting tail: w[16] window -> s4 (smooth c..c+3), d4 (detail).
static __device__ __forceinline__ void hcompute(const float w[16], int c,
                                                float4* s4, float4* d4) {
    // window: E[c-2+i] = w[2i], O[c-2+i] = w[2i+1], i = 0..7
    // dd[t] = global d[c-1+t], t = 0..5
    float dd[6];
    #pragma unroll
    for (int t = 0; t < 6; ++t)
        dd[t] = w[2*t+3] - 0.5f * (w[2*t] + w[2*t+4]);
    if (c == 0)   { dd[1] = w[5]  - w[6]; dd[0] = dd[2]; }   // d[0]=O0-E1; d[-1]->d[1]
    if (c == 508) { dd[4] = w[11] - w[8]; dd[5] = dd[3]; }   // d[511]=O511-E510; d[512]->d[510]
    float ss[4];
    #pragma unroll
    for (int i = 0; i < 4; ++i)
        ss[i] = w[2*i+4] + 0.25f * (dd[i] + dd[i+2]);
    *s4 = make_float4(ss[0], ss[1], ss[2], ss[3]);
    *d4 = make_float4(dd[1], dd[2], dd[3], dd[4]);
}

__global__ __launch_bounds__(256, 1) void ilwt53_v7(const float* __restrict__ x,
                                                    float* __restrict__ out) {
    const int tid = threadIdx.x;
    const int c0  = blockIdx.x * 32;   // half-res col origin (32 cols/block)
    const int r0  = blockIdx.y * 32;   // half-res row origin (32 rows/block)
    const int img = blockIdx.z;        // b*3 + ch

    const float* __restrict__ xim = x + (size_t)img * (1024 * 1024);

    const int rr = tid >> 3, ccg = tid & 7;
    const int r  = r0 + rr;
    const int c  = c0 + 4 * ccg;

    // Vertical stencil indices (half-res, reflected)
    const int k1 = mref(r - 1), k2 = mref(r + 1);
    const int ka = mref(k1 - 1), kd = mref(k2 + 1);
    // SE[m(k1+1)] == SE[r] except r==0 (-> SE[kd]); SE[m(k2-1)] == SE[r]
    // except r==511 (-> SE[ka]).

    // 8 full-res rows: 5 even (SE/DE at ka,k1,r,k2,kd), 3 odd (SO/DO at k1,r,k2)
    int rows[8];
    rows[0] = 2 * ka;     rows[1] = 2 * k1;     rows[2] = 2 * r;
    rows[3] = 2 * k2;     rows[4] = 2 * kd;
    rows[5] = 2 * k1 + 1; rows[6] = 2 * r + 1;  rows[7] = 2 * k2 + 1;

    // ---- Load phase: all 32 float4 loads issued up front ----
    const int fb = 2 * c - 4;                      // 16-float window base
    float w[8][16];
    if (fb >= 0 && fb + 15 <= 1023) {              // interior (uniform per thread)
        #pragma unroll
        for (int i = 0; i < 8; ++i) {
            const float4* p = (const float4*)(xim + (size_t)rows[i] * 1024 + fb);
            float4 a = p[0], b = p[1], cc = p[2], d = p[3];
            w[i][0]  = a.x;  w[i][1]  = a.y;  w[i][2]  = a.z;  w[i][3]  = a.w;
            w[i][4]  = b.x;  w[i][5]  = b.y;  w[i][6]  = b.z;  w[i][7]  = b.w;
            w[i][8]  = cc.x; w[i][9]  = cc.y; w[i][10] = cc.z; w[i][11] = cc.w;
            w[i][12] = d.x;  w[i][13] = d.y;  w[i][14] = d.z;  w[i][15] = d.w;
        }
    } else {                                       // image edge: clamped scalars
        #pragma unroll
        for (int i = 0; i < 8; ++i) {
            const float* rp = xim + (size_t)rows[i] * 1024;
            #pragma unroll
            for (int t = 0; t < 16; ++t) {
                int gx = fb + t; gx = gx < 0 ? 0 : (gx > 1023 ? 1023 : gx);
                w[i][t] = rp[gx];
            }
        }
    }

    // ---- Horizontal lifting per row ----
    float4 S[8], D[8];
    #pragma unroll
    for (int i = 0; i < 8; ++i)
        hcompute(w[i], c, &S[i], &D[i]);

    const float4 se_a = S[0], se_1 = S[1], se_r = S[2], se_2 = S[3], se_d = S[4];
    const float4 so_1 = S[5], so_r = S[6], so_2 = S[7];
    const float4 de_a = D[0], de_1 = D[1], de_r = D[2], de_2 = D[3], de_d = D[4];
    const float4 do_1 = D[5], do_r = D[6], do_2 = D[7];

    const float4 seB = (r == 0)   ? se_d : se_r;   // SE[m(k1+1)]
    const float4 seE = (r == 511) ? se_a : se_r;   // SE[m(k2-1)]
    const float4 deB = (r == 0)   ? de_d : de_r;
    const float4 deE = (r == 511) ? de_a : de_r;

    // ---- Vertical lifting (v5-verified) ----
    const float4 lh_m = lift_sub(so_1, se_a, seB);
    const float4 lh_c = lift_sub(so_r, se_1, se_2);
    const float4 lh_p = lift_sub(so_2, seE, se_d);
    const float4 ll   = lift_add(se_r, lh_m, lh_p);
    const float4 hh_m = lift_sub(do_1, de_a, deB);
    const float4 hh_c = lift_sub(do_r, de_1, de_2);
    const float4 hh_p = lift_sub(do_2, deE, de_d);
    const float4 hl   = lift_add(de_r, hh_m, hh_p);

    const size_t plane = 512 * 512;
    float* __restrict__ ob = out + ((size_t)(img / 3) * 12 + (img % 3)) * plane;
    const size_t o = (size_t)r * 512 + c;
    *(float4*)(ob + o)             = ll;
    *(float4*)(ob + o + 3 * plane) = lh_c;
    *(float4*)(ob + o + 6 * plane) = hl;
    *(float4*)(ob + o + 9 * plane) = hh_c;
}

extern "C" void kernel_launch(void* const* d_in, const int* in_sizes, int n_in,
                              void* d_out, int out_size, void* d_ws, size_t ws_size,
                              hipStream_t stream) {
    const float* x = (const float*)d_in[0];
    float* out = (float*)d_out;
    dim3 grid(16, 16, 24);   // 16x16 half-res tiles per image, 24 images
    dim3 block(256);
    hipLaunchKernelGGL(ilwt53_v7, grid, block, 0, stream, x, out);
}

// Round 6
// 184.673 us; speedup vs baseline: 2.2598x; 2.2598x over previous
//
#include <hip/hip_runtime.h>

// 2D CDF 5/3 lifting wavelet, fused. Input x: (24,1024,1024) fp32.
// Output: (8,12,512,512) fp32, planes LL(0..2) LH(3..5) HL(6..8) HH(9..11).
//
// v8: WAVE-AUTONOMOUS tiles -- LDS staging, ZERO barriers.
// Evidence: v2/v4/v6 (LDS + __syncthreads) all 60-64us at ~50% of achievable
// HBM across occupancy 28-72%, 1-2 barriers, coalesced or strided loads.
// Theory: the block-wide barrier's vmcnt(0) drain phase-locks waves into
// load-burst / dead-HBM-window / store-burst convoys. v5/v7 (no LDS) broke
// on VGPR economics, not on the theory. Here each WAVE owns an 8-row x
// 32-col half-res tile with a private LDS slab:
//   Phase A: 96 items (24 staged full-res rows x 4 col-groups), v2's
//            verified horizontal lifting, ds_write to the wave's slab.
//   Phase B: v4's verified merged vertical pass, 4 float4 stores.
// Same-wave LDS write->read ordering is guaranteed by lgkmcnt (compiler-
// inserted); no cross-wave sharing exists, so NO __syncthreads anywhere.
// Waves drift out of phase -> no CU-wide dead HBM windows.
// LDS 27.6KB/block -> 5 blocks/CU = 20 waves; VGPR ~like v2 (44).

static __device__ __forceinline__ int mref(int k) {
    // _rpad reflect in half-res index space (N=512): e[-1]->E[1], e[512]->E[510]
    return k < 0 ? 1 : (k > 511 ? 510 : k);
}

static __device__ __forceinline__ float4 lift_sub(float4 o, float4 em, float4 ep) {
    float4 r;
    r.x = o.x - 0.5f * (em.x + ep.x);
    r.y = o.y - 0.5f * (em.y + ep.y);
    r.z = o.z - 0.5f * (em.z + ep.z);
    r.w = o.w - 0.5f * (em.w + ep.w);
    return r;
}

static __device__ __forceinline__ float4 lift_add(float4 e, float4 dm, float4 dp) {
    float4 r;
    r.x = e.x + 0.25f * (dm.x + dp.x);
    r.y = e.y + 0.25f * (dm.y + dp.y);
    r.z = e.z + 0.25f * (dm.z + dp.z);
    r.w = e.w + 0.25f * (dm.w + dp.w);
    return r;
}

__global__ __launch_bounds__(256) void ilwt53_v8(const float* __restrict__ x,
                                                 float* __restrict__ out) {
    const int tid  = threadIdx.x;
    const int lane = tid & 63;
    const int wv   = tid >> 6;               // wave 0..3
    const int c0   = blockIdx.x * 32;        // half-res col origin
    const int R0   = blockIdx.y * 32 + wv * 8;  // wave-owned half-res row origin
    const int img  = blockIdx.z;             // b*3 + ch
    const int rb   = 2 * R0 - 4;             // staged full-res row base

    // Per-wave slabs: 24 rows x stride 36 floats (32 data + 4 pad, keeps b128
    // alignment and staggers banks). No cross-wave sharing.
    __shared__ float sS[4][24 * 36];
    __shared__ float sD[4][24 * 36];
    float* __restrict__ wS = sS[wv];
    float* __restrict__ wD = sD[wv];

    const float* __restrict__ xim = x + (size_t)img * (1024 * 1024);

    // ---- Phase A: global -> regs (horizontal lifting) -> wave slab ----
    // 24 rows x 4 col-groups = 96 items over 64 lanes (2 exec-masked rounds).
    // All rows actually read in Phase B satisfy gy == 2k (or 2k+1) exactly;
    // clamped rows are never read (algebraic property of mref + halo size).
    #pragma unroll
    for (int it = 0; it < 2; ++it) {
        int i = lane + it * 64;
        if (i < 96) {
            int lr = i >> 2, g = i & 3;
            int gy = rb + lr; gy = gy < 0 ? 0 : (gy > 1023 ? 1023 : gy);
            const float* __restrict__ row = xim + (size_t)gy * 1024;
            int c  = c0 + 8 * g;       // first owned half-res col
            int fb = 2 * c - 4;        // 24-float full-res window base (16B aligned)

            float w[24];
            if (fb >= 0 && fb + 23 <= 1023) {
                const float4* p = (const float4*)(row + fb);
                #pragma unroll
                for (int q = 0; q < 6; ++q) {
                    float4 v = p[q];
                    w[4*q] = v.x; w[4*q+1] = v.y; w[4*q+2] = v.z; w[4*q+3] = v.w;
                }
            } else {
                #pragma unroll
                for (int q = 0; q < 24; ++q) {
                    int gx = fb + q; gx = gx < 0 ? 0 : (gx > 1023 ? 1023 : gx);
                    w[q] = row[gx];
                }
            }
            // window: E[c-2+u] = w[2u], O[c-2+u] = w[2u+1], u = 0..11
            float d[10];
            #pragma unroll
            for (int t = 0; t < 10; ++t)
                d[t] = w[2*t+3] - 0.5f * (w[2*t] + w[2*t+4]);
            if (c == 0)   d[1] = w[5]  - w[6];    // global j=0
            if (c == 504) d[8] = w[19] - w[16];   // global j=511
            float s[8];
            #pragma unroll
            for (int i2 = 0; i2 < 8; ++i2)
                s[i2] = w[2*i2+4] + 0.25f * (d[i2] + d[i2+2]);
            if (c == 0)   s[0] = w[4]  + 0.5f * d[2];
            if (c == 504) s[7] = w[18] + 0.5f * d[7];

            float4* ps = (float4*)(wS + lr * 36 + 8 * g);
            ps[0] = make_float4(s[0], s[1], s[2], s[3]);
            ps[1] = make_float4(s[4], s[5], s[6], s[7]);
            float4* pd = (float4*)(wD + lr * 36 + 8 * g);
            pd[0] = make_float4(d[1], d[2], d[3], d[4]);
            pd[1] = make_float4(d[5], d[6], d[7], d[8]);
        }
    }
    // NO __syncthreads: same-wave ds_write -> ds_read ordering via lgkmcnt.

    // ---- Phase B: merged vertical pass (v4-verified math), 64 items ----
    {
        const int rr = lane >> 3, ccg = lane & 7;
        const int r  = R0 + rr;
        const int k1 = mref(r - 1), k2 = mref(r + 1);
        const int ka = mref(k1 - 1), kb = mref(k1 + 1);
        const int kc = mref(k2 - 1), kd = mref(k2 + 1);
        const int co = 4 * ccg;

        // local slab row of SE[k]/DE[k] is 2*(k-R0)+4, of SO[k]/DO[k] is +5;
        // all k above fall in [R0-2, R0+9] -> rows 0..23.
        #define SE_(k) (*(const float4*)(wS + (2 * ((k) - R0) + 4) * 36 + co))
        #define SO_(k) (*(const float4*)(wS + (2 * ((k) - R0) + 5) * 36 + co))
        #define DE_(k) (*(const float4*)(wD + (2 * ((k) - R0) + 4) * 36 + co))
        #define DO_(k) (*(const float4*)(wD + (2 * ((k) - R0) + 5) * 36 + co))

        const size_t plane = 512 * 512;
        float* __restrict__ ob = out + ((size_t)(img / 3) * 12 + (img % 3)) * plane;
        const size_t o = (size_t)r * 512 + c0 + co;

        // L side
        {
            float4 se_r  = SE_(r);
            float4 se_k1 = SE_(k1);
            float4 se_k2 = SE_(k2);
            float4 se_a  = SE_(ka);
            float4 se_b  = SE_(kb);
            float4 se_c  = SE_(kc);
            float4 se_d  = SE_(kd);
            float4 so_r  = SO_(r);
            float4 so_k1 = SO_(k1);
            float4 so_k2 = SO_(k2);

            float4 lh_c = lift_sub(so_r,  se_k1, se_k2);   // LH[r]
            float4 lh_m = lift_sub(so_k1, se_a,  se_b);    // LH[m(r-1)]
            float4 lh_p = lift_sub(so_k2, se_c,  se_d);    // LH[m(r+1)]
            float4 ll   = lift_add(se_r, lh_m, lh_p);

            *(float4*)(ob + o)             = ll;           // LL plane
            *(float4*)(ob + o + 3 * plane) = lh_c;         // LH plane
        }
        // H side
        {
            float4 de_r  = DE_(r);
            float4 de_k1 = DE_(k1);
            float4 de_k2 = DE_(k2);
            float4 de_a  = DE_(ka);
            float4 de_b  = DE_(kb);
            float4 de_c  = DE_(kc);
            float4 de_d  = DE_(kd);
            float4 do_r  = DO_(r);
            float4 do_k1 = DO_(k1);
            float4 do_k2 = DO_(k2);

            float4 hh_c = lift_sub(do_r,  de_k1, de_k2);   // HH[r]
            float4 hh_m = lift_sub(do_k1, de_a,  de_b);    // HH[m(r-1)]
            float4 hh_p = lift_sub(do_k2, de_c,  de_d);    // HH[m(r+1)]
            float4 hl   = lift_add(de_r, hh_m, hh_p);

            *(float4*)(ob + o + 6 * plane) = hl;           // HL plane
            *(float4*)(ob + o + 9 * plane) = hh_c;         // HH plane
        }
        #undef SE_
        #undef SO_
        #undef DE_
        #undef DO_
    }
}

extern "C" void kernel_launch(void* const* d_in, const int* in_sizes, int n_in,
                              void* d_out, int out_size, void* d_ws, size_t ws_size,
                              hipStream_t stream) {
    const float* x = (const float*)d_in[0];
    float* out = (float*)d_out;
    dim3 grid(16, 16, 24);   // 16x16 half-res tiles per image, 24 images
    dim3 block(256);
    hipLaunchKernelGGL(ilwt53_v8, grid, block, 0, stream, x, out);
}

// Round 7
// 175.976 us; speedup vs baseline: 2.3715x; 1.0494x over previous
//
#include <hip/hip_runtime.h>

// 2D CDF 5/3 lifting wavelet, fused. Input x: (24,1024,1024) fp32.
// Output: (8,12,512,512) fp32, planes LL(0..2) LH(3..5) HL(6..8) HH(9..11).
//
// v9 = v2 (best measured base, 60.2us) + XCD-chunked bijective blockIdx
// swizzle (T1). Eliminated non-levers: barriers (v8), coalescing (v6),
// occupancy 28-72% (v2-v4), LDS vs no-LDS (v5/v7), VGPR 28-128. All
// variants 60-66us = 2x copy roofline, FETCH/WRITE ideal, VALU <17%.
// Remaining theory: grid (16,16,24) round-robins the 16 x-tiles sharing
// each 4KB image row (one DRAM page) across 8 XCDs -> every XCD's L2 miss
// stream is scattered 288B slivers from interleaved pages -> HBM page/bank
// efficiency ~halves. Swizzle W=(D%8)*768+D/8 (x-fastest work order) gives
// each XCD 3 whole images swept sequentially: dense per-XCD miss streams,
// plus y-halo L2 reuse. Intra-block structure is v2 verbatim.

static __device__ __forceinline__ int mref(int k) {
    // _rpad reflect in half-res index space (N=512): e[-1]->E[1], e[512]->E[510]
    return k < 0 ? 1 : (k > 511 ? 510 : k);
}

__global__ __launch_bounds__(256) void ilwt53_v9(const float* __restrict__ x,
                                                 float* __restrict__ out) {
    const int tid = threadIdx.x;

    // ---- XCD-chunked bijective swizzle (6144 blocks, 8 XCDs, 768/XCD) ----
    const int D = blockIdx.x + 16 * blockIdx.y + 256 * blockIdx.z;  // hw id
    const int W = (D & 7) * 768 + (D >> 3);                          // work id
    const int bx  = W & 15;
    const int by  = (W >> 4) & 15;
    const int img = W >> 8;            // b*3 + ch

    const int c0  = bx * 32;           // half-res col origin
    const int r0  = by * 32;           // half-res row origin
    const int rb  = 2 * r0 - 4;        // full-res row base (4-row halo)

    // row stride 36 floats: keeps b128 alignment and offsets bank phases
    __shared__ float sS[72 * 36];      // horizontal smooth, full-res row lr
    __shared__ float sD[72 * 36];      // horizontal detail
    __shared__ float sLH[34 * 36];     // vertical LH rows, j = k-(r0-1)
    __shared__ float sHH[34 * 36];     // vertical HH rows

    const float* __restrict__ xim = x + (size_t)img * (1024 * 1024);

    // ---- Phase A: global -> registers (horizontal lifting) -> LDS ----
    // 72 rows x 4 col-groups = 288 items; item owns half-res cols c..c+7.
    #pragma unroll
    for (int it = 0; it < 2; ++it) {
        int i = tid + it * 256;
        if (i < 288) {
            int lr = i >> 2, g = i & 3;
            int gy = rb + lr; gy = gy < 0 ? 0 : (gy > 1023 ? 1023 : gy);
            const float* __restrict__ row = xim + (size_t)gy * 1024;
            int c  = c0 + 8 * g;       // first owned half-res col
            int fb = 2 * c - 4;        // 24-float full-res window base (16B aligned)

            float w[24];
            if (fb >= 0 && fb + 23 <= 1023) {
                const float4* p = (const float4*)(row + fb);
                #pragma unroll
                for (int q = 0; q < 6; ++q) {
                    float4 v = p[q];
                    w[4*q] = v.x; w[4*q+1] = v.y; w[4*q+2] = v.z; w[4*q+3] = v.w;
                }
            } else {
                #pragma unroll
                for (int q = 0; q < 24; ++q) {
                    int gx = fb + q; gx = gx < 0 ? 0 : (gx > 1023 ? 1023 : gx);
                    w[q] = row[gx];
                }
            }
            // window layout: E[c-2+u] = w[2u], O[c-2+u] = w[2u+1], u = 0..11
            float d[10];
            #pragma unroll
            for (int t = 0; t < 10; ++t)
                d[t] = w[2*t+3] - 0.5f * (w[2*t] + w[2*t+4]);
            // horizontal image-edge fixes: d[0] = O[0]-E[1]; d[511] = O[511]-E[510]
            if (c == 0)   d[1] = w[5]  - w[6];    // global j=0  (t=1)
            if (c == 504) d[8] = w[19] - w[16];   // global j=511 (t=8)

            float s[8];
            #pragma unroll
            for (int i2 = 0; i2 < 8; ++i2)
                s[i2] = w[2*i2+4] + 0.25f * (d[i2] + d[i2+2]);
            // s edge fixes: s[0] uses d[m(-1)]=d[1] twice; s[511] uses d[510] twice
            if (c == 0)   s[0] = w[4]  + 0.5f * d[2];   // d[2] is global d[1]
            if (c == 504) s[7] = w[18] + 0.5f * d[7];   // d[7] is global d[510]

            float4* ps = (float4*)(sS + lr * 36 + 8 * g);
            ps[0] = make_float4(s[0], s[1], s[2], s[3]);
            ps[1] = make_float4(s[4], s[5], s[6], s[7]);
            float4* pd = (float4*)(sD + lr * 36 + 8 * g);
            pd[0] = make_float4(d[1], d[2], d[3], d[4]);   // global d[c..c+3]
            pd[1] = make_float4(d[5], d[6], d[7], d[8]);   // global d[c+4..c+7]
        }
    }
    __syncthreads();

    // ---- Phase B1: LH/HH rows into LDS ----
    // 34 k-rows x 8 col-groups = 272 items; each computes LH and HH for 4 cols.
    #pragma unroll
    for (int it = 0; it < 2; ++it) {
        int i = tid + it * 256;
        if (i < 272) {
            int j = i >> 3, ccg = i & 7;
            int k  = r0 - 1 + j;
            int km = mref(k - 1), kp = mref(k + 1);
            int lo = 2 * (k  - r0) + 5;   // SO(k) local full-res row
            int lm = 2 * (km - r0) + 4;   // SE(km)
            int lp = 2 * (kp - r0) + 4;   // SE(kp)
            int co = 4 * ccg;
            float4 so  = *(const float4*)(sS + lo * 36 + co);
            float4 sem = *(const float4*)(sS + lm * 36 + co);
            float4 sep = *(const float4*)(sS + lp * 36 + co);
            float4 dv  = *(const float4*)(sD + lo * 36 + co);
            float4 dem = *(const float4*)(sD + lm * 36 + co);
            float4 dep = *(const float4*)(sD + lp * 36 + co);
            float4 lh, hh;
            lh.x = so.x - 0.5f * (sem.x + sep.x);
            lh.y = so.y - 0.5f * (sem.y + sep.y);
            lh.z = so.z - 0.5f * (sem.z + sep.z);
            lh.w = so.w - 0.5f * (sem.w + sep.w);
            hh.x = dv.x - 0.5f * (dem.x + dep.x);
            hh.y = dv.y - 0.5f * (dem.y + dep.y);
            hh.z = dv.z - 0.5f * (dem.z + dep.z);
            hh.w = dv.w - 0.5f * (dem.w + dep.w);
            *(float4*)(sLH + j * 36 + co) = lh;
            *(float4*)(sHH + j * 36 + co) = hh;
        }
    }
    __syncthreads();

    // ---- Phase B2: LL/HL + gather, 4 float4 stores ----
    {
        int rr = tid >> 3, ccg = tid & 7;
        int r  = r0 + rr;
        int km = mref(r - 1), kp = mref(r + 1);
        int jm = km - (r0 - 1), jc = rr + 1, jp = kp - (r0 - 1);
        int le = 2 * rr + 4;              // SE(r)/DE(r) local full-res row
        int co = 4 * ccg;
        float4 se  = *(const float4*)(sS  + le * 36 + co);
        float4 de  = *(const float4*)(sD  + le * 36 + co);
        float4 lhm = *(const float4*)(sLH + jm * 36 + co);
        float4 lhc = *(const float4*)(sLH + jc * 36 + co);
        float4 lhp = *(const float4*)(sLH + jp * 36 + co);
        float4 hhm = *(const float4*)(sHH + jm * 36 + co);
        float4 hhc = *(const float4*)(sHH + jc * 36 + co);
        float4 hhp = *(const float4*)(sHH + jp * 36 + co);
        float4 ll, hl;
        ll.x = se.x + 0.25f * (lhm.x + lhp.x);
        ll.y = se.y + 0.25f * (lhm.y + lhp.y);
        ll.z = se.z + 0.25f * (lhm.z + lhp.z);
        ll.w = se.w + 0.25f * (lhm.w + lhp.w);
        hl.x = de.x + 0.25f * (hhm.x + hhp.x);
        hl.y = de.y + 0.25f * (hhm.y + hhp.y);
        hl.z = de.z + 0.25f * (hhm.z + hhp.z);
        hl.w = de.w + 0.25f * (hhm.w + hhp.w);

        const size_t plane = 512 * 512;
        float* __restrict__ ob = out + ((size_t)(img / 3) * 12 + (img % 3)) * plane;
        size_t o = (size_t)r * 512 + c0 + co;
        *(float4*)(ob + o)             = ll;
        *(float4*)(ob + o + 3 * plane) = lhc;
        *(float4*)(ob + o + 6 * plane) = hl;
        *(float4*)(ob + o + 9 * plane) = hhc;
    }
}

extern "C" void kernel_launch(void* const* d_in, const int* in_sizes, int n_in,
                              void* d_out, int out_size, void* d_ws, size_t ws_size,
                              hipStream_t stream) {
    const float* x = (const float*)d_in[0];
    float* out = (float*)d_out;
    dim3 grid(16, 16, 24);   // 16x16 half-res tiles per image, 24 images
    dim3 block(256);
    hipLaunchKernelGGL(ilwt53_v9, grid, block, 0, stream, x, out);
}